// Round 2
// baseline (4858.915 us; speedup 1.0000x reference)
//
#include <hip/hip_runtime.h>

#define H_ 160
#define W_ 160
#define CIN 32
#define COUT 32
#define HW_ (H_ * W_)

// Fused deformable conv v1:
//  stage 1: offset conv (3x3, Cin=32 -> 18 offset channels) per pixel
//  stage 2: bilinear deformable sampling + (Cin*9 x 32) matmul + ReLU
// One thread = one output pixel (all 32 output channels in registers).
// CRITICAL: both tap loops are fully unrolled so off[]/acc[] are indexed by
// compile-time constants only -> stay in VGPRs. R1 left the tap loop rolled,
// off[2*tap] was a dynamic index, the whole array spilled to scratch and
// WRITE_SIZE hit 5 GB (3106 us).
__global__ __launch_bounds__(256, 2) void dcn_fused(
    const float* __restrict__ x,      // (8, 32, 160, 160)
    const float* __restrict__ w_off,  // (18, 32, 3, 3)
    const float* __restrict__ b_off,  // (18,)
    const float* __restrict__ w_dcn,  // (32, 32, 3, 3)
    float* __restrict__ out)          // (8, 32, 160, 160)
{
    __shared__ float wdcn_lds[9 * 32 * 32];  // [tap][c][o]
    __shared__ float woff_lds[9 * 32 * 20];  // [tap][c][j], j padded 18->20
    __shared__ float boff_lds[20];

    const int tid = threadIdx.x;

    // ---- stage weights into LDS (destination-order fill, no races) ----
    for (int d = tid; d < 9 * 32 * 32; d += 256) {
        int tap = d >> 10, c = (d >> 5) & 31, o = d & 31;
        wdcn_lds[d] = w_dcn[(o * 32 + c) * 9 + tap];
    }
    for (int d = tid; d < 9 * 32 * 20; d += 256) {
        int tap = d / 640, c = (d / 20) & 31, j = d % 20;
        woff_lds[d] = (j < 18) ? w_off[(j * 32 + c) * 9 + tap] : 0.0f;
    }
    if (tid < 18) boff_lds[tid] = b_off[tid];
    __syncthreads();

    const int pix = blockIdx.x * 256 + tid;
    const int w = pix % W_;
    const int h = (pix / W_) % H_;
    const int b = pix / HW_;
    const float* __restrict__ xb = x + (size_t)b * CIN * HW_;

    // ---- stage 1: offset conv -> off[0..17] (dy=off[2t], dx=off[2t+1]) ----
    float off[20];
    #pragma unroll
    for (int j = 0; j < 20; ++j) off[j] = 0.0f;

    #pragma unroll
    for (int tap = 0; tap < 9; ++tap) {
        const int yy = h - 1 + tap / 3;
        const int xx = w - 1 + tap % 3;
        const bool valid = (yy >= 0) && (yy < H_) && (xx >= 0) && (xx < W_);
        const int idx = valid ? (yy * W_ + xx) : 0;
        const float* __restrict__ wl = &woff_lds[tap * 32 * 20];
        for (int c = 0; c < 32; ++c) {
            float xv = valid ? xb[c * HW_ + idx] : 0.0f;
            const float4* w4 = (const float4*)(wl + c * 20);
            #pragma unroll
            for (int q = 0; q < 5; ++q) {
                float4 wv = w4[q];
                off[4 * q + 0] = fmaf(xv, wv.x, off[4 * q + 0]);
                off[4 * q + 1] = fmaf(xv, wv.y, off[4 * q + 1]);
                off[4 * q + 2] = fmaf(xv, wv.z, off[4 * q + 2]);
                off[4 * q + 3] = fmaf(xv, wv.w, off[4 * q + 3]);
            }
        }
    }
    #pragma unroll
    for (int j = 0; j < 18; ++j) off[j] += boff_lds[j];

    // ---- stage 2: deformable sampling + matmul ----
    float acc[32];
    #pragma unroll
    for (int o = 0; o < 32; ++o) acc[o] = 0.0f;

    #pragma unroll
    for (int tap = 0; tap < 9; ++tap) {
        const float py = (float)(h - 1 + tap / 3) + off[2 * tap];
        const float px = (float)(w - 1 + tap % 3) + off[2 * tap + 1];
        const float fy0 = floorf(py), fx0 = floorf(px);
        const float wy1 = py - fy0, wx1 = px - fx0;
        const float wy0 = 1.0f - wy1, wx0 = 1.0f - wx1;
        const int y0 = (int)fy0, x0 = (int)fx0;
        const int y1 = y0 + 1, x1 = x0 + 1;
        const bool vy0 = (y0 >= 0) && (y0 < H_);
        const bool vy1 = (y1 >= 0) && (y1 < H_);
        const bool vx0 = (x0 >= 0) && (x0 < W_);
        const bool vx1 = (x1 >= 0) && (x1 < W_);
        const float w00 = (vy0 && vx0) ? wy0 * wx0 : 0.0f;
        const float w01 = (vy0 && vx1) ? wy0 * wx1 : 0.0f;
        const float w10 = (vy1 && vx0) ? wy1 * wx0 : 0.0f;
        const float w11 = (vy1 && vx1) ? wy1 * wx1 : 0.0f;
        const int yc0 = min(max(y0, 0), H_ - 1), yc1 = min(max(y1, 0), H_ - 1);
        const int xc0 = min(max(x0, 0), W_ - 1), xc1 = min(max(x1, 0), W_ - 1);
        const int i00 = yc0 * W_ + xc0, i01 = yc0 * W_ + xc1;
        const int i10 = yc1 * W_ + xc0, i11 = yc1 * W_ + xc1;
        const float* __restrict__ wl = &wdcn_lds[tap * 32 * 32];
        for (int c = 0; c < 32; ++c) {
            const float* __restrict__ xc = xb + c * HW_;
            float v = w00 * xc[i00] + w01 * xc[i01] + w10 * xc[i10] + w11 * xc[i11];
            const float4* w4 = (const float4*)(wl + c * 32);
            #pragma unroll
            for (int q = 0; q < 8; ++q) {
                float4 wv = w4[q];
                acc[4 * q + 0] = fmaf(v, wv.x, acc[4 * q + 0]);
                acc[4 * q + 1] = fmaf(v, wv.y, acc[4 * q + 1]);
                acc[4 * q + 2] = fmaf(v, wv.z, acc[4 * q + 2]);
                acc[4 * q + 3] = fmaf(v, wv.w, acc[4 * q + 3]);
            }
        }
    }

    // ---- epilogue: ReLU + store ----
    float* __restrict__ ob = out + (size_t)b * COUT * HW_ + h * W_ + w;
    #pragma unroll
    for (int o = 0; o < 32; ++o) {
        ob[o * HW_] = fmaxf(acc[o], 0.0f);
    }
}

extern "C" void kernel_launch(void* const* d_in, const int* in_sizes, int n_in,
                              void* d_out, int out_size, void* d_ws, size_t ws_size,
                              hipStream_t stream) {
    const float* x     = (const float*)d_in[0];
    const float* w_off = (const float*)d_in[1];
    const float* b_off = (const float*)d_in[2];
    const float* w_dcn = (const float*)d_in[3];
    float* out = (float*)d_out;

    // 8*160*160 pixels / 256 threads = 800 blocks exactly
    dcn_fused<<<800, 256, 0, stream>>>(x, w_off, b_off, w_dcn, out);
}

// Round 3
// 330.530 us; speedup vs baseline: 14.7004x; 14.7004x over previous
//
#include <hip/hip_runtime.h>

#define H_ 160
#define W_ 160
#define CIN 32
#define COUT 32
#define HW_ (H_ * W_)
#define NPIX (8 * HW_)   // 204800 pixels total

// ============================================================================
// Two-kernel deformable conv. NO private arrays anywhere: every accumulator is
// a distinct named scalar, so nothing can be demoted to scratch (R1/R2 showed
// 5 GB/dispatch scratch write traffic from array demotion -> 3-5 ms).
// Offsets go through d_ws in planar [j][pix] layout (14.7 MB) so both kernels
// keep small live state and all global traffic is coalesced.
// ============================================================================

// ---------------- Kernel A: 3x3 offset conv (Cin=32 -> 18 channels) --------
__global__ __launch_bounds__(256, 4) void dcn_offset(
    const float* __restrict__ x,      // (8, 32, 160, 160)
    const float* __restrict__ w_off,  // (18, 32, 3, 3)
    const float* __restrict__ b_off,  // (18,)
    float* __restrict__ off_ws)       // [18][NPIX]
{
    __shared__ __align__(16) float wl[9 * 32 * 20];  // [tap][c][j], j padded to 20
    __shared__ float bl[18];
    const int tid = threadIdx.x;
    for (int d = tid; d < 9 * 32 * 20; d += 256) {
        int tap = d / 640, c = (d / 20) % 32, j = d % 20;
        wl[d] = (j < 18) ? w_off[(j * 32 + c) * 9 + tap] : 0.0f;
    }
    if (tid < 18) bl[tid] = b_off[tid];
    __syncthreads();

    const int pix = blockIdx.x * 256 + tid;
    const int w = pix % W_;
    const int h = (pix / W_) % H_;
    const int b = pix / HW_;
    const float* __restrict__ xb = x + (size_t)b * CIN * HW_;

    float a0 = 0, a1 = 0, a2 = 0, a3 = 0, a4 = 0, a5 = 0, a6 = 0, a7 = 0, a8 = 0;
    float a9 = 0, a10 = 0, a11 = 0, a12 = 0, a13 = 0, a14 = 0, a15 = 0, a16 = 0, a17 = 0;

    for (int tap = 0; tap < 9; ++tap) {
        const int yy = h - 1 + tap / 3;
        const int xx = w - 1 + tap % 3;
        const bool valid = (yy >= 0) && (yy < H_) && (xx >= 0) && (xx < W_);
        const int idx = valid ? (yy * W_ + xx) : 0;
        const float* __restrict__ wt = &wl[tap * 640];
        #pragma unroll 2
        for (int c = 0; c < 32; ++c) {
            const float xv = valid ? xb[c * HW_ + idx] : 0.0f;
            const float* __restrict__ wc = wt + c * 20;
            float4 q;
            q = *(const float4*)(wc);
            a0 = fmaf(xv, q.x, a0);  a1 = fmaf(xv, q.y, a1);
            a2 = fmaf(xv, q.z, a2);  a3 = fmaf(xv, q.w, a3);
            q = *(const float4*)(wc + 4);
            a4 = fmaf(xv, q.x, a4);  a5 = fmaf(xv, q.y, a5);
            a6 = fmaf(xv, q.z, a6);  a7 = fmaf(xv, q.w, a7);
            q = *(const float4*)(wc + 8);
            a8 = fmaf(xv, q.x, a8);  a9 = fmaf(xv, q.y, a9);
            a10 = fmaf(xv, q.z, a10); a11 = fmaf(xv, q.w, a11);
            q = *(const float4*)(wc + 12);
            a12 = fmaf(xv, q.x, a12); a13 = fmaf(xv, q.y, a13);
            a14 = fmaf(xv, q.z, a14); a15 = fmaf(xv, q.w, a15);
            const float2 q2 = *(const float2*)(wc + 16);
            a16 = fmaf(xv, q2.x, a16); a17 = fmaf(xv, q2.y, a17);
        }
    }

    off_ws[ 0 * NPIX + pix] = a0  + bl[0];
    off_ws[ 1 * NPIX + pix] = a1  + bl[1];
    off_ws[ 2 * NPIX + pix] = a2  + bl[2];
    off_ws[ 3 * NPIX + pix] = a3  + bl[3];
    off_ws[ 4 * NPIX + pix] = a4  + bl[4];
    off_ws[ 5 * NPIX + pix] = a5  + bl[5];
    off_ws[ 6 * NPIX + pix] = a6  + bl[6];
    off_ws[ 7 * NPIX + pix] = a7  + bl[7];
    off_ws[ 8 * NPIX + pix] = a8  + bl[8];
    off_ws[ 9 * NPIX + pix] = a9  + bl[9];
    off_ws[10 * NPIX + pix] = a10 + bl[10];
    off_ws[11 * NPIX + pix] = a11 + bl[11];
    off_ws[12 * NPIX + pix] = a12 + bl[12];
    off_ws[13 * NPIX + pix] = a13 + bl[13];
    off_ws[14 * NPIX + pix] = a14 + bl[14];
    off_ws[15 * NPIX + pix] = a15 + bl[15];
    off_ws[16 * NPIX + pix] = a16 + bl[16];
    off_ws[17 * NPIX + pix] = a17 + bl[17];
}

// ------ Kernel B: bilinear deformable sampling + 32-ch matmul + ReLU --------
__global__ __launch_bounds__(256, 4) void dcn_sample(
    const float* __restrict__ x,       // (8, 32, 160, 160)
    const float* __restrict__ w_dcn,   // (32, 32, 3, 3)
    const float* __restrict__ off_ws,  // [18][NPIX]
    float* __restrict__ out)           // (8, 32, 160, 160)
{
    __shared__ __align__(16) float wl[9 * 32 * 32];  // [tap][c][o]
    const int tid = threadIdx.x;
    for (int d = tid; d < 9 * 32 * 32; d += 256) {
        int tap = d >> 10, c = (d >> 5) & 31, o = d & 31;
        wl[d] = w_dcn[(o * 32 + c) * 9 + tap];
    }
    __syncthreads();

    const int pix = blockIdx.x * 256 + tid;
    const int w = pix % W_;
    const int h = (pix / W_) % H_;
    const int b = pix / HW_;
    const float* __restrict__ xb = x + (size_t)b * CIN * HW_;

    float s0 = 0, s1 = 0, s2 = 0, s3 = 0, s4 = 0, s5 = 0, s6 = 0, s7 = 0;
    float s8 = 0, s9 = 0, s10 = 0, s11 = 0, s12 = 0, s13 = 0, s14 = 0, s15 = 0;
    float s16 = 0, s17 = 0, s18 = 0, s19 = 0, s20 = 0, s21 = 0, s22 = 0, s23 = 0;
    float s24 = 0, s25 = 0, s26 = 0, s27 = 0, s28 = 0, s29 = 0, s30 = 0, s31 = 0;

    for (int tap = 0; tap < 9; ++tap) {
        const float dy = off_ws[(2 * tap) * NPIX + pix];
        const float dx = off_ws[(2 * tap + 1) * NPIX + pix];
        const float py = (float)(h - 1 + tap / 3) + dy;
        const float px = (float)(w - 1 + tap % 3) + dx;
        const float fy0 = floorf(py), fx0 = floorf(px);
        const float wy1 = py - fy0, wx1 = px - fx0;
        const float wy0 = 1.0f - wy1, wx0 = 1.0f - wx1;
        const int y0 = (int)fy0, x0 = (int)fx0;
        const int y1 = y0 + 1, x1 = x0 + 1;
        const bool vy0 = (y0 >= 0) && (y0 < H_);
        const bool vy1 = (y1 >= 0) && (y1 < H_);
        const bool vx0 = (x0 >= 0) && (x0 < W_);
        const bool vx1 = (x1 >= 0) && (x1 < W_);
        const float w00 = (vy0 && vx0) ? wy0 * wx0 : 0.0f;
        const float w01 = (vy0 && vx1) ? wy0 * wx1 : 0.0f;
        const float w10 = (vy1 && vx0) ? wy1 * wx0 : 0.0f;
        const float w11 = (vy1 && vx1) ? wy1 * wx1 : 0.0f;
        const int yc0 = min(max(y0, 0), H_ - 1), yc1 = min(max(y1, 0), H_ - 1);
        const int xc0 = min(max(x0, 0), W_ - 1), xc1 = min(max(x1, 0), W_ - 1);
        const int i00 = yc0 * W_ + xc0, i01 = yc0 * W_ + xc1;
        const int i10 = yc1 * W_ + xc0, i11 = yc1 * W_ + xc1;
        const float* __restrict__ wt = &wl[tap * 1024];
        #pragma unroll 2
        for (int c = 0; c < 32; ++c) {
            const float* __restrict__ xc = xb + c * HW_;
            const float v = w00 * xc[i00] + w01 * xc[i01]
                          + w10 * xc[i10] + w11 * xc[i11];
            const float* __restrict__ wc = wt + (c << 5);
            float4 q;
            q = *(const float4*)(wc);
            s0 = fmaf(v, q.x, s0);   s1 = fmaf(v, q.y, s1);
            s2 = fmaf(v, q.z, s2);   s3 = fmaf(v, q.w, s3);
            q = *(const float4*)(wc + 4);
            s4 = fmaf(v, q.x, s4);   s5 = fmaf(v, q.y, s5);
            s6 = fmaf(v, q.z, s6);   s7 = fmaf(v, q.w, s7);
            q = *(const float4*)(wc + 8);
            s8 = fmaf(v, q.x, s8);   s9 = fmaf(v, q.y, s9);
            s10 = fmaf(v, q.z, s10); s11 = fmaf(v, q.w, s11);
            q = *(const float4*)(wc + 12);
            s12 = fmaf(v, q.x, s12); s13 = fmaf(v, q.y, s13);
            s14 = fmaf(v, q.z, s14); s15 = fmaf(v, q.w, s15);
            q = *(const float4*)(wc + 16);
            s16 = fmaf(v, q.x, s16); s17 = fmaf(v, q.y, s17);
            s18 = fmaf(v, q.z, s18); s19 = fmaf(v, q.w, s19);
            q = *(const float4*)(wc + 20);
            s20 = fmaf(v, q.x, s20); s21 = fmaf(v, q.y, s21);
            s22 = fmaf(v, q.z, s22); s23 = fmaf(v, q.w, s23);
            q = *(const float4*)(wc + 24);
            s24 = fmaf(v, q.x, s24); s25 = fmaf(v, q.y, s25);
            s26 = fmaf(v, q.z, s26); s27 = fmaf(v, q.w, s27);
            q = *(const float4*)(wc + 28);
            s28 = fmaf(v, q.x, s28); s29 = fmaf(v, q.y, s29);
            s30 = fmaf(v, q.z, s30); s31 = fmaf(v, q.w, s31);
        }
    }

    float* __restrict__ ob = out + (size_t)b * COUT * HW_ + h * W_ + w;
    ob[ 0 * HW_] = fmaxf(s0, 0.0f);   ob[ 1 * HW_] = fmaxf(s1, 0.0f);
    ob[ 2 * HW_] = fmaxf(s2, 0.0f);   ob[ 3 * HW_] = fmaxf(s3, 0.0f);
    ob[ 4 * HW_] = fmaxf(s4, 0.0f);   ob[ 5 * HW_] = fmaxf(s5, 0.0f);
    ob[ 6 * HW_] = fmaxf(s6, 0.0f);   ob[ 7 * HW_] = fmaxf(s7, 0.0f);
    ob[ 8 * HW_] = fmaxf(s8, 0.0f);   ob[ 9 * HW_] = fmaxf(s9, 0.0f);
    ob[10 * HW_] = fmaxf(s10, 0.0f);  ob[11 * HW_] = fmaxf(s11, 0.0f);
    ob[12 * HW_] = fmaxf(s12, 0.0f);  ob[13 * HW_] = fmaxf(s13, 0.0f);
    ob[14 * HW_] = fmaxf(s14, 0.0f);  ob[15 * HW_] = fmaxf(s15, 0.0f);
    ob[16 * HW_] = fmaxf(s16, 0.0f);  ob[17 * HW_] = fmaxf(s17, 0.0f);
    ob[18 * HW_] = fmaxf(s18, 0.0f);  ob[19 * HW_] = fmaxf(s19, 0.0f);
    ob[20 * HW_] = fmaxf(s20, 0.0f);  ob[21 * HW_] = fmaxf(s21, 0.0f);
    ob[22 * HW_] = fmaxf(s22, 0.0f);  ob[23 * HW_] = fmaxf(s23, 0.0f);
    ob[24 * HW_] = fmaxf(s24, 0.0f);  ob[25 * HW_] = fmaxf(s25, 0.0f);
    ob[26 * HW_] = fmaxf(s26, 0.0f);  ob[27 * HW_] = fmaxf(s27, 0.0f);
    ob[28 * HW_] = fmaxf(s28, 0.0f);  ob[29 * HW_] = fmaxf(s29, 0.0f);
    ob[30 * HW_] = fmaxf(s30, 0.0f);  ob[31 * HW_] = fmaxf(s31, 0.0f);
}

extern "C" void kernel_launch(void* const* d_in, const int* in_sizes, int n_in,
                              void* d_out, int out_size, void* d_ws, size_t ws_size,
                              hipStream_t stream) {
    const float* x     = (const float*)d_in[0];
    const float* w_off = (const float*)d_in[1];
    const float* b_off = (const float*)d_in[2];
    const float* w_dcn = (const float*)d_in[3];
    float* out    = (float*)d_out;
    float* off_ws = (float*)d_ws;   // needs 18*204800*4 = 14.75 MB

    dcn_offset<<<800, 256, 0, stream>>>(x, w_off, b_off, off_ws);
    dcn_sample<<<800, 256, 0, stream>>>(x, w_dcn, off_ws, out);
}